// Round 6
// baseline (1625.298 us; speedup 1.0000x reference)
//
#include <hip/hip_runtime.h>
#include <hip/hip_bf16.h>

typedef __attribute__((ext_vector_type(8))) short short8;
typedef __attribute__((ext_vector_type(4))) float floatx4;
typedef __attribute__((ext_vector_type(4))) unsigned short ushortx4;

__device__ __forceinline__ float bf2f(unsigned short u) {
    union { float f; unsigned int i; } v; v.i = ((unsigned int)u) << 16; return v.f;
}
__device__ __forceinline__ unsigned short f2bf(float f) {
    union { float f; unsigned int i; } v; v.f = f;
    unsigned int r = v.i + 0x7fffu + ((v.i >> 16) & 1u);
    return (unsigned short)(r >> 16);
}

// ---------------------------------------------------------------------------
// CSR build: degree histogram -> chunked block scan -> scatter.
// CSR slot j gets: eix[j] = original edge id, sx[j] = src node, dstS[j] = dst.
// ---------------------------------------------------------------------------
__global__ void deg_count(const int* __restrict__ dst, int* __restrict__ deg, int E) {
    int i = blockIdx.x * 256 + threadIdx.x;
    if (i < E) atomicAdd(&deg[dst[i]], 1);
}

__global__ __launch_bounds__(1024) void scan_rowptr(const int* __restrict__ deg,
                                                    int* __restrict__ rowptr,
                                                    int* __restrict__ cursor, int N) {
    const int CH = 20;  // 1024*20 = 20480 >= N
    __shared__ int buf[1024];
    int t = threadIdx.x;
    int base = t * CH;
    int local[CH];
    int tot = 0;
#pragma unroll
    for (int k = 0; k < CH; ++k) {
        int i = base + k;
        int v = (i < N) ? deg[i] : 0;
        local[k] = tot;
        tot += v;
    }
    buf[t] = tot;
    __syncthreads();
    for (int off = 1; off < 1024; off <<= 1) {
        int x = (t >= off) ? buf[t - off] : 0;
        __syncthreads();
        buf[t] += x;
        __syncthreads();
    }
    int excl = buf[t] - tot;
#pragma unroll
    for (int k = 0; k < CH; ++k) {
        int i = base + k;
        if (i < N) { rowptr[i] = excl + local[k]; cursor[i] = excl + local[k]; }
    }
    if (t == 1023) rowptr[N] = buf[1023];
}

__global__ void scatter_edges(const int* __restrict__ src, const int* __restrict__ dst,
                              int* __restrict__ cursor, int* __restrict__ eix,
                              int* __restrict__ sx, int* __restrict__ dstS, int E) {
    int i = blockIdx.x * 256 + threadIdx.x;
    if (i >= E) return;
    int d = dst[i];
    int pos = atomicAdd(&cursor[d], 1);
    eix[pos] = i;
    sx[pos] = src[i];
    dstS[pos] = d;
}

// ---------------------------------------------------------------------------
// Weight pre-transpose + bf16 convert: Wt[slot][n*128+k] = bf16(W[slot][k*128+n])
// ---------------------------------------------------------------------------
__global__ void transpose_w(const float* __restrict__ Wh,
                            const float* __restrict__ We,
                            const float* __restrict__ Aw,
                            const float* __restrict__ Bw,
                            const float* __restrict__ Cw,
                            const float* __restrict__ Dw,
                            const float* __restrict__ Ew,
                            unsigned short* __restrict__ Wt) {
    int i = blockIdx.x * 256 + threadIdx.x;
    const int total = 22 * 16384;
    if (i >= total) return;
    int slot = i >> 14;
    int r = i & 16383;
    int n = r >> 7;
    int k = r & 127;
    const float* srcp;
    if (slot == 0) srcp = Wh;
    else if (slot == 1) srcp = We;
    else {
        int t = slot - 2;
        int l = t / 5, w = t % 5;
        const float* bases[5] = {Aw, Bw, Cw, Dw, Ew};
        srcp = bases[w] + l * 16384;
    }
    Wt[i] = f2bf(srcp[k * 128 + n]);
}

// ---------------------------------------------------------------------------
// Generic GEMM for the two embeddings. GATHER: A row index via ridx.
// ---------------------------------------------------------------------------
template <int OUT_BF16, int GATHER>
__global__ __launch_bounds__(256) void gemm128(const float* __restrict__ Af,
                                               const int* __restrict__ ridx,
                                               const unsigned short* __restrict__ Wt,
                                               const float* __restrict__ bias,
                                               void* __restrict__ Cout, int nStrips) {
    const int lane = threadIdx.x & 63;
    const int wv = threadIdx.x >> 6;
    const int m16 = lane & 15;
    const int kg = lane >> 4;

    short8 b[4][8];
#pragma unroll
    for (int ks = 0; ks < 4; ++ks)
#pragma unroll
        for (int nt = 0; nt < 8; ++nt)
            b[ks][nt] = *(const short8*)(Wt + (nt * 16 + m16) * 128 + ks * 32 + kg * 8);

    float bv[8];
#pragma unroll
    for (int nt = 0; nt < 8; ++nt) bv[nt] = bias[nt * 16 + m16];

    int wave = blockIdx.x * 4 + wv;
    int nw = gridDim.x * 4;
    for (int s = wave; s < nStrips; s += nw) {
        int rowA = s * 16 + m16;
        if (GATHER) rowA = ridx[rowA];
        size_t rowBase = (size_t)rowA * 128;
        short8 a[4];
#pragma unroll
        for (int ks = 0; ks < 4; ++ks) {
            int off = ks * 32 + kg * 8;
            floatx4 f0 = *(const floatx4*)(Af + rowBase + off);
            floatx4 f1 = *(const floatx4*)(Af + rowBase + off + 4);
            short8 t;
            t[0] = (short)f2bf(f0[0]); t[1] = (short)f2bf(f0[1]);
            t[2] = (short)f2bf(f0[2]); t[3] = (short)f2bf(f0[3]);
            t[4] = (short)f2bf(f1[0]); t[5] = (short)f2bf(f1[1]);
            t[6] = (short)f2bf(f1[2]); t[7] = (short)f2bf(f1[3]);
            a[ks] = t;
        }
        floatx4 acc[8];
#pragma unroll
        for (int nt = 0; nt < 8; ++nt) acc[nt] = (floatx4){0.f, 0.f, 0.f, 0.f};
#pragma unroll
        for (int ks = 0; ks < 4; ++ks)
#pragma unroll
            for (int nt = 0; nt < 8; ++nt)
                acc[nt] = __builtin_amdgcn_mfma_f32_16x16x32_bf16(a[ks], b[ks][nt], acc[nt], 0, 0, 0);
#pragma unroll
        for (int nt = 0; nt < 8; ++nt) {
#pragma unroll
            for (int i = 0; i < 4; ++i) {
                size_t r = (size_t)s * 16 + kg * 4 + i;
                int cix = nt * 16 + m16;
                float v = acc[nt][i] + bv[nt];
                if (OUT_BF16)
                    ((unsigned short*)Cout)[r * 128 + cix] = f2bf(v);
                else
                    ((float*)Cout)[r * 128 + cix] = v;
            }
        }
    }
}

// ---------------------------------------------------------------------------
// Quad h-GEMM: Ah (fp32), Bh/Dh/Eh (bf16 tables for gathers).
// ---------------------------------------------------------------------------
__global__ __launch_bounds__(256) void gemm_h4(const float* __restrict__ h_cur,
                                               const unsigned short* __restrict__ WtL,
                                               const float* __restrict__ Abi,
                                               const float* __restrict__ Bbi,
                                               const float* __restrict__ Dbi,
                                               const float* __restrict__ Ebi,
                                               float* __restrict__ AhB,
                                               unsigned short* __restrict__ Bh16,
                                               unsigned short* __restrict__ Dh16,
                                               unsigned short* __restrict__ Eh16,
                                               int nStrips) {
    const int lane = threadIdx.x & 63;
    const int wv = threadIdx.x >> 6;
    const int m16 = lane & 15;
    const int kg = lane >> 4;
    int s = blockIdx.x;
    if (s >= nStrips) return;

    const int slotmap[4] = {0, 1, 3, 4};
    const unsigned short* Wm = WtL + slotmap[wv] * 16384;
    const float* biasp = (wv == 0) ? Abi : (wv == 1) ? Bbi : (wv == 2) ? Dbi : Ebi;

    short8 b[4][8];
#pragma unroll
    for (int ks = 0; ks < 4; ++ks)
#pragma unroll
        for (int nt = 0; nt < 8; ++nt)
            b[ks][nt] = *(const short8*)(Wm + (nt * 16 + m16) * 128 + ks * 32 + kg * 8);
    float bv[8];
#pragma unroll
    for (int nt = 0; nt < 8; ++nt) bv[nt] = biasp[nt * 16 + m16];

    size_t rowBase = ((size_t)s * 16 + m16) * 128;
    short8 a[4];
#pragma unroll
    for (int ks = 0; ks < 4; ++ks) {
        int off = ks * 32 + kg * 8;
        floatx4 f0 = *(const floatx4*)(h_cur + rowBase + off);
        floatx4 f1 = *(const floatx4*)(h_cur + rowBase + off + 4);
        short8 t;
        t[0] = (short)f2bf(f0[0]); t[1] = (short)f2bf(f0[1]);
        t[2] = (short)f2bf(f0[2]); t[3] = (short)f2bf(f0[3]);
        t[4] = (short)f2bf(f1[0]); t[5] = (short)f2bf(f1[1]);
        t[6] = (short)f2bf(f1[2]); t[7] = (short)f2bf(f1[3]);
        a[ks] = t;
    }
    floatx4 acc[8];
#pragma unroll
    for (int nt = 0; nt < 8; ++nt) acc[nt] = (floatx4){0.f, 0.f, 0.f, 0.f};
#pragma unroll
    for (int ks = 0; ks < 4; ++ks)
#pragma unroll
        for (int nt = 0; nt < 8; ++nt)
            acc[nt] = __builtin_amdgcn_mfma_f32_16x16x32_bf16(a[ks], b[ks][nt], acc[nt], 0, 0, 0);

    unsigned short* out16 = (wv == 1) ? Bh16 : (wv == 2) ? Dh16 : Eh16;
#pragma unroll
    for (int nt = 0; nt < 8; ++nt)
#pragma unroll
        for (int i = 0; i < 4; ++i) {
            size_t r = (size_t)s * 16 + kg * 4 + i;
            int c = nt * 16 + m16;
            float v = acc[nt][i] + bv[nt];
            if (wv == 0) AhB[r * 128 + c] = v;
            else out16[r * 128 + c] = f2bf(v);
        }
}

// ---------------------------------------------------------------------------
// Fused e-GEMM + prev-layer e_update + edge gate. SWAPPED MFMA OPERANDS:
// acc = mfma(W_frag, e_frag) computes D[n][edge]: each lane owns ONE edge
// (col = m16) and 4 consecutive n per tile (n = nt*16+kg*4+i) -> 8-byte
// vectorized gathers/stores. Weights staged in LDS (stride 136 vs banks).
// e-BN stats are computed later in node_aggregate (each edge read once).
// ---------------------------------------------------------------------------
template <int IN_UPDATE, int WRITE_ECUR>
__global__ __launch_bounds__(256, 4) void egemm_gate(unsigned short* __restrict__ e_cur,
                                                     const unsigned short* __restrict__ Wt,
                                                     const float* __restrict__ bias,
                                                     const unsigned short* __restrict__ Dh16,
                                                     const unsigned short* __restrict__ Eh16,
                                                     const int* __restrict__ sx,
                                                     const int* __restrict__ dstS,
                                                     unsigned short* __restrict__ e_new,
                                                     const float* __restrict__ coefE,
                                                     int nStrips) {
    __shared__ unsigned short Ws[128 * 136];
    {
        int n = threadIdx.x >> 1;
        int k0 = (threadIdx.x & 1) * 64;
#pragma unroll
        for (int k = 0; k < 64; k += 8) {
            short8 w = *(const short8*)(Wt + n * 128 + k0 + k);
            *(short8*)(Ws + n * 136 + k0 + k) = w;
        }
    }
    __syncthreads();

    const int lane = threadIdx.x & 63;
    const int wv = threadIdx.x >> 6;
    const int m16 = lane & 15;
    const int kg = lane >> 4;

    floatx4 bv[8];
#pragma unroll
    for (int nt = 0; nt < 8; ++nt) bv[nt] = *(const floatx4*)(bias + nt * 16 + kg * 4);

    int wave = blockIdx.x * 4 + wv;
    int nw = gridDim.x * 4;
    for (int s = wave; s < nStrips; s += nw) {
        int r_edge = s * 16 + m16;
        int sr = sx[r_edge];
        int dr = dstS[r_edge];
        size_t rowBase = (size_t)r_edge * 128;
        short8 a[4];
#pragma unroll
        for (int ks = 0; ks < 4; ++ks) {
            int off = ks * 32 + kg * 8;
            short8 ec = *(const short8*)(e_cur + rowBase + off);
            if (IN_UPDATE) {
                short8 en = *(const short8*)(e_new + rowBase + off);
                floatx4 sa0 = *(const floatx4*)(coefE + 256 + off);
                floatx4 sa1 = *(const floatx4*)(coefE + 256 + off + 4);
                floatx4 sb0 = *(const floatx4*)(coefE + 384 + off);
                floatx4 sb1 = *(const floatx4*)(coefE + 384 + off + 4);
                short8 t;
#pragma unroll
                for (int k = 0; k < 8; ++k) {
                    float sa = (k < 4) ? sa0[k] : sa1[k - 4];
                    float sb = (k < 4) ? sb0[k] : sb1[k - 4];
                    float v = bf2f((unsigned short)en[k]) * sa + sb;
                    v = v > 0.f ? v : 0.f;
                    t[k] = (short)f2bf(bf2f((unsigned short)ec[k]) + v);
                }
                if (WRITE_ECUR) *(short8*)(e_cur + rowBase + off) = t;
                a[ks] = t;
            } else {
                a[ks] = ec;
            }
        }
        floatx4 acc[8];
#pragma unroll
        for (int nt = 0; nt < 8; ++nt) acc[nt] = (floatx4){0.f, 0.f, 0.f, 0.f};
#pragma unroll
        for (int ks = 0; ks < 4; ++ks) {
#pragma unroll
            for (int nt = 0; nt < 8; ++nt) {
                short8 w = *(const short8*)(Ws + (nt * 16 + m16) * 136 + ks * 32 + kg * 8);
                acc[nt] = __builtin_amdgcn_mfma_f32_16x16x32_bf16(w, a[ks], acc[nt], 0, 0, 0);
            }
        }
        const unsigned short* dp = Dh16 + (size_t)sr * 128;
        const unsigned short* ep = Eh16 + (size_t)dr * 128;
#pragma unroll
        for (int nt = 0; nt < 8; ++nt) {
            int c0 = nt * 16 + kg * 4;
            ushortx4 d4 = *(const ushortx4*)(dp + c0);
            ushortx4 e4 = *(const ushortx4*)(ep + c0);
            ushortx4 o;
#pragma unroll
            for (int i = 0; i < 4; ++i) {
                float v = acc[nt][i] + bv[nt][i] + bf2f(d4[i]) + bf2f(e4[i]);
                o[i] = f2bf(v);
            }
            *(ushortx4*)(e_new + rowBase + c0) = o;
        }
    }
}

// ---------------------------------------------------------------------------
// CSR aggregation + node combine + h-BN stats + e-BN stats.
// e_new rows for node d are CONTIGUOUS (CSR): rowptr[d]..rowptr[d+1].
// 32 lanes per node, 4 cols/lane.
// ---------------------------------------------------------------------------
__global__ __launch_bounds__(256) void node_aggregate(const unsigned short* __restrict__ e_new,
                                                      const unsigned short* __restrict__ Bh16,
                                                      const int* __restrict__ rowptr,
                                                      const int* __restrict__ sx,
                                                      const float* __restrict__ Ah,
                                                      float* __restrict__ h_new,
                                                      float* __restrict__ sums, int N) {
    const int q = threadIdx.x & 31;
    const int g = threadIdx.x >> 5;
    float hs[4] = {0.f, 0.f, 0.f, 0.f};
    float hq[4] = {0.f, 0.f, 0.f, 0.f};
    float es[4] = {0.f, 0.f, 0.f, 0.f};
    float eq[4] = {0.f, 0.f, 0.f, 0.f};
    for (int d = blockIdx.x * 8 + g; d < N; d += gridDim.x * 8) {
        int beg = rowptr[d], end = rowptr[d + 1];
        float num[4] = {0.f, 0.f, 0.f, 0.f};
        float den[4] = {0.f, 0.f, 0.f, 0.f};
        for (int j = beg; j < end; ++j) {
            int s = sx[j];
            ushortx4 ev = *(const ushortx4*)(e_new + (size_t)j * 128 + q * 4);
            ushortx4 bh = *(const ushortx4*)(Bh16 + (size_t)s * 128 + q * 4);
#pragma unroll
            for (int k = 0; k < 4; ++k) {
                float en = bf2f(ev[k]);
                es[k] += en;
                eq[k] += en * en;
                float sg = 1.f / (1.f + __expf(-en));
                den[k] += sg;
                num[k] += sg * bf2f(bh[k]);
            }
        }
        floatx4 ah = *(const floatx4*)(Ah + (size_t)d * 128 + q * 4);
        floatx4 out;
#pragma unroll
        for (int k = 0; k < 4; ++k) {
            float v = ah[k] + num[k] / (den[k] + 1e-6f);
            out[k] = v;
            hs[k] += v;
            hq[k] += v * v;
        }
        *(floatx4*)(h_new + (size_t)d * 128 + q * 4) = out;
    }
    __shared__ float ls[512];
    ls[threadIdx.x] = 0.f;
    ls[256 + threadIdx.x] = 0.f;
    __syncthreads();
#pragma unroll
    for (int k = 0; k < 4; ++k) {
        atomicAdd(&ls[q * 4 + k], hs[k]);
        atomicAdd(&ls[128 + q * 4 + k], hq[k]);
        atomicAdd(&ls[256 + q * 4 + k], es[k]);
        atomicAdd(&ls[384 + q * 4 + k], eq[k]);
    }
    __syncthreads();
    atomicAdd(&sums[threadIdx.x], ls[threadIdx.x]);
    atomicAdd(&sums[256 + threadIdx.x], ls[256 + threadIdx.x]);
}

// ---------------------------------------------------------------------------
// Finalize BN stats -> affine coefs.
// ---------------------------------------------------------------------------
__global__ void finalize_stats(const float* __restrict__ sums,
                               const float* __restrict__ gh,
                               const float* __restrict__ bh,
                               const float* __restrict__ ge,
                               const float* __restrict__ be,
                               float* __restrict__ coef, int N, int E) {
    int c = threadIdx.x;
    if (c >= 128) return;
    float muh = sums[c] / (float)N;
    float vh = fmaxf(sums[128 + c] / (float)N - muh * muh, 0.f);
    float rsh = rsqrtf(vh + 1e-5f);
    float g = gh[c], bt = bh[c];
    coef[c] = g * rsh;
    coef[128 + c] = bt - g * rsh * muh;
    float mue = sums[256 + c] / (float)E;
    float ve = fmaxf(sums[384 + c] / (float)E - mue * mue, 0.f);
    float rse = rsqrtf(ve + 1e-5f);
    float g2 = ge[c], b2 = be[c];
    coef[256 + c] = g2 * rse;
    coef[384 + c] = b2 - g2 * rse * mue;
}

// ---------------------------------------------------------------------------
// h residual update.
// ---------------------------------------------------------------------------
__global__ __launch_bounds__(256) void h_update(const float* __restrict__ h_new,
                                                const float* __restrict__ coef,
                                                float* __restrict__ h_cur,
                                                float* __restrict__ out, int N) {
    const int c = threadIdx.x & 127;
    float sa = coef[c], sb = coef[128 + c];
    int total = N * 128;
    for (int i = blockIdx.x * blockDim.x + threadIdx.x; i < total; i += gridDim.x * blockDim.x) {
        float v = h_new[i] * sa + sb;
        v = v > 0.f ? v : 0.f;
        float h = h_cur[i] + v;
        h_cur[i] = h;
        if (out) out[i] = h;
    }
}

extern "C" void kernel_launch(void* const* d_in, const int* in_sizes, int n_in,
                              void* d_out, int out_size, void* d_ws, size_t ws_size,
                              hipStream_t stream) {
    const int N = 20000, E = 256000, L = 4;

    const float* h_in = (const float*)d_in[0];
    const float* e_in = (const float*)d_in[1];
    const int* src = (const int*)d_in[2];
    const int* dst = (const int*)d_in[3];
    const float* Wemb_h = (const float*)d_in[4];
    const float* bemb_h = (const float*)d_in[5];
    const float* Wemb_e = (const float*)d_in[6];
    const float* bemb_e = (const float*)d_in[7];
    const float* Aw = (const float*)d_in[8];
    const float* Abi = (const float*)d_in[9];
    const float* Bw = (const float*)d_in[10];
    const float* Bbi = (const float*)d_in[11];
    const float* Cw = (const float*)d_in[12];
    const float* Cbi = (const float*)d_in[13];
    const float* Dw = (const float*)d_in[14];
    const float* Dbi = (const float*)d_in[15];
    const float* Ew = (const float*)d_in[16];
    const float* Ebi = (const float*)d_in[17];
    const float* gh = (const float*)d_in[18];
    const float* bh = (const float*)d_in[19];
    const float* ge = (const float*)d_in[20];
    const float* be = (const float*)d_in[21];

    char* p = (char*)d_ws;
    auto carve = [&](size_t bytes) {
        void* r = (void*)p;
        p += ((bytes + 255) & ~(size_t)255);
        return r;
    };
    unsigned short* Wt = (unsigned short*)carve((size_t)22 * 16384 * 2);
    float* h_cur = (float*)carve((size_t)N * 128 * 4);
    unsigned short* e_cur = (unsigned short*)carve((size_t)E * 128 * 2);   // CSR order
    unsigned short* e_new = (unsigned short*)carve((size_t)E * 128 * 2);   // CSR order
    float* AhB = (float*)carve((size_t)N * 128 * 4);
    unsigned short* Bh16 = (unsigned short*)carve((size_t)N * 128 * 2);
    unsigned short* Dh16 = (unsigned short*)carve((size_t)N * 128 * 2);
    unsigned short* Eh16 = (unsigned short*)carve((size_t)N * 128 * 2);
    float* h_newB = (float*)carve((size_t)N * 128 * 4);
    float* sums = (float*)carve(4 * 128 * 4);
    float* coef = (float*)carve(4 * 128 * 4);
    int* deg = (int*)carve((size_t)N * 4);
    int* rowptr = (int*)carve((size_t)(N + 1) * 4);
    int* cursor = (int*)carve((size_t)N * 4);
    int* eix = (int*)carve((size_t)E * 4);
    int* sx = (int*)carve((size_t)E * 4);
    int* dstS = (int*)carve((size_t)E * 4);

    // ---- CSR build ----
    hipMemsetAsync(deg, 0, (size_t)N * 4, stream);
    deg_count<<<(E + 255) / 256, 256, 0, stream>>>(dst, deg, E);
    scan_rowptr<<<1, 1024, 0, stream>>>(deg, rowptr, cursor, N);
    scatter_edges<<<(E + 255) / 256, 256, 0, stream>>>(src, dst, cursor, eix, sx, dstS, E);

    // weights -> transposed bf16 layout
    transpose_w<<<(22 * 16384 + 255) / 256, 256, 0, stream>>>(Wemb_h, Wemb_e, Aw, Bw, Cw, Dw, Ew, Wt);

    // input embeddings: h normal; e gathered into CSR order (bf16 out)
    gemm128<0, 0><<<313, 256, 0, stream>>>(h_in, nullptr, Wt + 0 * 16384, bemb_h, h_cur, N / 16);
    gemm128<1, 1><<<2048, 256, 0, stream>>>(e_in, eix, Wt + 1 * 16384, bemb_e, e_cur, E / 16);

    for (int l = 0; l < L; ++l) {
        int last = (l == L - 1);
        hipMemsetAsync(sums, 0, 4 * 128 * 4, stream);
        const unsigned short* WtL = Wt + (size_t)(2 + l * 5) * 16384;
        gemm_h4<<<N / 16, 256, 0, stream>>>(h_cur, WtL, Abi + l * 128, Bbi + l * 128,
                                            Dbi + l * 128, Ebi + l * 128, AhB, Bh16, Dh16, Eh16,
                                            N / 16);
        if (l == 0)
            egemm_gate<0, 0><<<1024, 256, 0, stream>>>(e_cur, WtL + 2 * 16384, Cbi + l * 128,
                                                       Dh16, Eh16, sx, dstS, e_new, coef, E / 16);
        else if (!last)
            egemm_gate<1, 1><<<1024, 256, 0, stream>>>(e_cur, WtL + 2 * 16384, Cbi + l * 128,
                                                       Dh16, Eh16, sx, dstS, e_new, coef, E / 16);
        else
            egemm_gate<1, 0><<<1024, 256, 0, stream>>>(e_cur, WtL + 2 * 16384, Cbi + l * 128,
                                                       Dh16, Eh16, sx, dstS, e_new, coef, E / 16);
        node_aggregate<<<1250, 256, 0, stream>>>(e_new, Bh16, rowptr, sx, AhB, h_newB, sums, N);
        finalize_stats<<<1, 128, 0, stream>>>(sums, gh + l * 128, bh + l * 128, ge + l * 128,
                                              be + l * 128, coef, N, E);
        h_update<<<512, 256, 0, stream>>>(h_newB, coef, h_cur, last ? (float*)d_out : nullptr, N);
    }
}

// Round 7
// 1118.449 us; speedup vs baseline: 1.4532x; 1.4532x over previous
//
#include <hip/hip_runtime.h>
#include <hip/hip_bf16.h>

typedef __attribute__((ext_vector_type(8))) short short8;
typedef __attribute__((ext_vector_type(4))) float floatx4;
typedef __attribute__((ext_vector_type(4))) unsigned short ushortx4;

__device__ __forceinline__ float bf2f(unsigned short u) {
    union { float f; unsigned int i; } v; v.i = ((unsigned int)u) << 16; return v.f;
}
__device__ __forceinline__ unsigned short f2bf(float f) {
    union { float f; unsigned int i; } v; v.f = f;
    unsigned int r = v.i + 0x7fffu + ((v.i >> 16) & 1u);
    return (unsigned short)(r >> 16);
}

// ---------------------------------------------------------------------------
// CSR build: degree histogram -> chunked block scan -> scatter.
// ---------------------------------------------------------------------------
__global__ void deg_count(const int* __restrict__ dst, int* __restrict__ deg, int E) {
    int i = blockIdx.x * 256 + threadIdx.x;
    if (i < E) atomicAdd(&deg[dst[i]], 1);
}

__global__ __launch_bounds__(1024) void scan_rowptr(const int* __restrict__ deg,
                                                    int* __restrict__ rowptr,
                                                    int* __restrict__ cursor, int N) {
    const int CH = 20;  // 1024*20 = 20480 >= N
    __shared__ int buf[1024];
    int t = threadIdx.x;
    int base = t * CH;
    int local[CH];
    int tot = 0;
#pragma unroll
    for (int k = 0; k < CH; ++k) {
        int i = base + k;
        int v = (i < N) ? deg[i] : 0;
        local[k] = tot;
        tot += v;
    }
    buf[t] = tot;
    __syncthreads();
    for (int off = 1; off < 1024; off <<= 1) {
        int x = (t >= off) ? buf[t - off] : 0;
        __syncthreads();
        buf[t] += x;
        __syncthreads();
    }
    int excl = buf[t] - tot;
#pragma unroll
    for (int k = 0; k < CH; ++k) {
        int i = base + k;
        if (i < N) { rowptr[i] = excl + local[k]; cursor[i] = excl + local[k]; }
    }
    if (t == 1023) rowptr[N] = buf[1023];
}

__global__ void scatter_edges(const int* __restrict__ src, const int* __restrict__ dst,
                              int* __restrict__ cursor, int* __restrict__ eix,
                              int* __restrict__ sx, int E) {
    int i = blockIdx.x * 256 + threadIdx.x;
    if (i >= E) return;
    int d = dst[i];
    int pos = atomicAdd(&cursor[d], 1);
    eix[pos] = i;
    sx[pos] = src[i];
}

// ---------------------------------------------------------------------------
// Weight pre-transpose + bf16 convert: Wt[slot][n*128+k] = bf16(W[slot][k*128+n])
// ---------------------------------------------------------------------------
__global__ void transpose_w(const float* __restrict__ Wh,
                            const float* __restrict__ We,
                            const float* __restrict__ Aw,
                            const float* __restrict__ Bw,
                            const float* __restrict__ Cw,
                            const float* __restrict__ Dw,
                            const float* __restrict__ Ew,
                            unsigned short* __restrict__ Wt) {
    int i = blockIdx.x * 256 + threadIdx.x;
    const int total = 22 * 16384;
    if (i >= total) return;
    int slot = i >> 14;
    int r = i & 16383;
    int n = r >> 7;
    int k = r & 127;
    const float* srcp;
    if (slot == 0) srcp = Wh;
    else if (slot == 1) srcp = We;
    else {
        int t = slot - 2;
        int l = t / 5, w = t % 5;
        const float* bases[5] = {Aw, Bw, Cw, Dw, Ew};
        srcp = bases[w] + l * 16384;
    }
    Wt[i] = f2bf(srcp[k * 128 + n]);
}

// ---------------------------------------------------------------------------
// Generic GEMM: C[M,128] = A[M,128]@W + bias. Register-resident B-frags.
// IN_BF16 / OUT_BF16 select dtypes; GATHER: A row index via ridx.
// ---------------------------------------------------------------------------
template <int IN_BF16, int OUT_BF16, int GATHER>
__global__ __launch_bounds__(256) void gemm128(const void* __restrict__ Ain,
                                               const int* __restrict__ ridx,
                                               const unsigned short* __restrict__ Wt,
                                               const float* __restrict__ bias,
                                               void* __restrict__ Cout, int nStrips) {
    const int lane = threadIdx.x & 63;
    const int wv = threadIdx.x >> 6;
    const int m16 = lane & 15;
    const int kg = lane >> 4;

    short8 b[4][8];
#pragma unroll
    for (int ks = 0; ks < 4; ++ks)
#pragma unroll
        for (int nt = 0; nt < 8; ++nt)
            b[ks][nt] = *(const short8*)(Wt + (nt * 16 + m16) * 128 + ks * 32 + kg * 8);

    float bv[8];
#pragma unroll
    for (int nt = 0; nt < 8; ++nt) bv[nt] = bias[nt * 16 + m16];

    const float* Af = (const float*)Ain;
    const unsigned short* Ab16 = (const unsigned short*)Ain;

    int wave = blockIdx.x * 4 + wv;
    int nw = gridDim.x * 4;
    for (int s = wave; s < nStrips; s += nw) {
        int rowA = s * 16 + m16;
        if (GATHER) rowA = ridx[rowA];
        size_t rowBase = (size_t)rowA * 128;
        short8 a[4];
#pragma unroll
        for (int ks = 0; ks < 4; ++ks) {
            int off = ks * 32 + kg * 8;
            if (IN_BF16) {
                a[ks] = *(const short8*)(Ab16 + rowBase + off);
            } else {
                floatx4 f0 = *(const floatx4*)(Af + rowBase + off);
                floatx4 f1 = *(const floatx4*)(Af + rowBase + off + 4);
                short8 t;
                t[0] = (short)f2bf(f0[0]); t[1] = (short)f2bf(f0[1]);
                t[2] = (short)f2bf(f0[2]); t[3] = (short)f2bf(f0[3]);
                t[4] = (short)f2bf(f1[0]); t[5] = (short)f2bf(f1[1]);
                t[6] = (short)f2bf(f1[2]); t[7] = (short)f2bf(f1[3]);
                a[ks] = t;
            }
        }
        floatx4 acc[8];
#pragma unroll
        for (int nt = 0; nt < 8; ++nt) acc[nt] = (floatx4){0.f, 0.f, 0.f, 0.f};
#pragma unroll
        for (int ks = 0; ks < 4; ++ks)
#pragma unroll
            for (int nt = 0; nt < 8; ++nt)
                acc[nt] = __builtin_amdgcn_mfma_f32_16x16x32_bf16(a[ks], b[ks][nt], acc[nt], 0, 0, 0);
#pragma unroll
        for (int nt = 0; nt < 8; ++nt) {
#pragma unroll
            for (int i = 0; i < 4; ++i) {
                size_t r = (size_t)s * 16 + kg * 4 + i;
                int cix = nt * 16 + m16;
                float v = acc[nt][i] + bv[nt];
                if (OUT_BF16)
                    ((unsigned short*)Cout)[r * 128 + cix] = f2bf(v);
                else
                    ((float*)Cout)[r * 128 + cix] = v;
            }
        }
    }
}

// ---------------------------------------------------------------------------
// Quad h-GEMM: Ah (fp32), BD16 packed (Bh even cols / Dh odd cols, 256/row),
// Eh16 (bf16). Block = 4 waves; wave wv handles matrix wv on strip blockIdx.x.
// ---------------------------------------------------------------------------
__global__ __launch_bounds__(256) void gemm_h4(const float* __restrict__ h_cur,
                                               const unsigned short* __restrict__ WtL,
                                               const float* __restrict__ Abi,
                                               const float* __restrict__ Bbi,
                                               const float* __restrict__ Dbi,
                                               const float* __restrict__ Ebi,
                                               float* __restrict__ AhB,
                                               unsigned short* __restrict__ BD16,
                                               unsigned short* __restrict__ Eh16,
                                               int nStrips) {
    const int lane = threadIdx.x & 63;
    const int wv = threadIdx.x >> 6;
    const int m16 = lane & 15;
    const int kg = lane >> 4;
    int s = blockIdx.x;
    if (s >= nStrips) return;

    const int slotmap[4] = {0, 1, 3, 4};  // A, B, D, E
    const unsigned short* Wm = WtL + slotmap[wv] * 16384;
    const float* biasp = (wv == 0) ? Abi : (wv == 1) ? Bbi : (wv == 2) ? Dbi : Ebi;

    short8 b[4][8];
#pragma unroll
    for (int ks = 0; ks < 4; ++ks)
#pragma unroll
        for (int nt = 0; nt < 8; ++nt)
            b[ks][nt] = *(const short8*)(Wm + (nt * 16 + m16) * 128 + ks * 32 + kg * 8);
    float bv[8];
#pragma unroll
    for (int nt = 0; nt < 8; ++nt) bv[nt] = biasp[nt * 16 + m16];

    size_t rowBase = ((size_t)s * 16 + m16) * 128;
    short8 a[4];
#pragma unroll
    for (int ks = 0; ks < 4; ++ks) {
        int off = ks * 32 + kg * 8;
        floatx4 f0 = *(const floatx4*)(h_cur + rowBase + off);
        floatx4 f1 = *(const floatx4*)(h_cur + rowBase + off + 4);
        short8 t;
        t[0] = (short)f2bf(f0[0]); t[1] = (short)f2bf(f0[1]);
        t[2] = (short)f2bf(f0[2]); t[3] = (short)f2bf(f0[3]);
        t[4] = (short)f2bf(f1[0]); t[5] = (short)f2bf(f1[1]);
        t[6] = (short)f2bf(f1[2]); t[7] = (short)f2bf(f1[3]);
        a[ks] = t;
    }
    floatx4 acc[8];
#pragma unroll
    for (int nt = 0; nt < 8; ++nt) acc[nt] = (floatx4){0.f, 0.f, 0.f, 0.f};
#pragma unroll
    for (int ks = 0; ks < 4; ++ks)
#pragma unroll
        for (int nt = 0; nt < 8; ++nt)
            acc[nt] = __builtin_amdgcn_mfma_f32_16x16x32_bf16(a[ks], b[ks][nt], acc[nt], 0, 0, 0);

#pragma unroll
    for (int nt = 0; nt < 8; ++nt)
#pragma unroll
        for (int i = 0; i < 4; ++i) {
            size_t r = (size_t)s * 16 + kg * 4 + i;
            int c = nt * 16 + m16;
            float v = acc[nt][i] + bv[nt];
            if (wv == 0) AhB[r * 128 + c] = v;
            else if (wv == 1) BD16[r * 256 + 2 * c] = f2bf(v);       // Bh
            else if (wv == 2) BD16[r * 256 + 2 * c + 1] = f2bf(v);   // Dh
            else Eh16[r * 128 + c] = f2bf(v);
        }
}

// ---------------------------------------------------------------------------
// Fused gate + CSR aggregation + node combine + BN stats.
// Edge j (CSR dst-order): e_new[j] = Ce[j] + Dh[sx[j]] + Eh[d]  (in place
// over Ce). Eh row loaded ONCE per node. BD16[s] rows are full-row coalesced
// 16B/lane gathers. 32 lanes per node, 4 cols/lane, 2-edge unroll.
// DO_E: write e_new + e-BN stats (off for last layer).
// ---------------------------------------------------------------------------
template <int DO_E>
__global__ __launch_bounds__(256) void node_aggregate(unsigned short* __restrict__ Ce,
                                                      const unsigned short* __restrict__ BD16,
                                                      const unsigned short* __restrict__ Eh16,
                                                      const int* __restrict__ rowptr,
                                                      const int* __restrict__ sx,
                                                      const float* __restrict__ Ah,
                                                      float* __restrict__ h_new,
                                                      float* __restrict__ sums, int N) {
    const int q = threadIdx.x & 31;
    const int g = threadIdx.x >> 5;
    float hs[4] = {0.f, 0.f, 0.f, 0.f};
    float hq[4] = {0.f, 0.f, 0.f, 0.f};
    float es[4] = {0.f, 0.f, 0.f, 0.f};
    float eq[4] = {0.f, 0.f, 0.f, 0.f};
    for (int d = blockIdx.x * 8 + g; d < N; d += gridDim.x * 8) {
        int beg = rowptr[d], end = rowptr[d + 1];
        ushortx4 eh4 = *(const ushortx4*)(Eh16 + (size_t)d * 128 + q * 4);
        float ehf[4];
#pragma unroll
        for (int k = 0; k < 4; ++k) ehf[k] = bf2f(eh4[k]);
        float num[4] = {0.f, 0.f, 0.f, 0.f};
        float den[4] = {0.f, 0.f, 0.f, 0.f};
        int j = beg;
        for (; j + 1 < end; j += 2) {
            int s0 = sx[j], s1 = sx[j + 1];
            ushortx4 c0 = *(const ushortx4*)(Ce + (size_t)j * 128 + q * 4);
            ushortx4 c1 = *(const ushortx4*)(Ce + (size_t)(j + 1) * 128 + q * 4);
            short8 bd0 = *(const short8*)(BD16 + (size_t)s0 * 256 + q * 8);
            short8 bd1 = *(const short8*)(BD16 + (size_t)s1 * 256 + q * 8);
            ushortx4 o0, o1;
#pragma unroll
            for (int k = 0; k < 4; ++k) {
                float en0 = bf2f(c0[k]) + bf2f((unsigned short)bd0[2 * k + 1]) + ehf[k];
                float en1 = bf2f(c1[k]) + bf2f((unsigned short)bd1[2 * k + 1]) + ehf[k];
                if (DO_E) {
                    es[k] += en0 + en1;
                    eq[k] += en0 * en0 + en1 * en1;
                    o0[k] = f2bf(en0);
                    o1[k] = f2bf(en1);
                }
                float sg0 = 1.f / (1.f + __expf(-en0));
                float sg1 = 1.f / (1.f + __expf(-en1));
                den[k] += sg0 + sg1;
                num[k] += sg0 * bf2f((unsigned short)bd0[2 * k])
                        + sg1 * bf2f((unsigned short)bd1[2 * k]);
            }
            if (DO_E) {
                *(ushortx4*)(Ce + (size_t)j * 128 + q * 4) = o0;
                *(ushortx4*)(Ce + (size_t)(j + 1) * 128 + q * 4) = o1;
            }
        }
        if (j < end) {
            int s0 = sx[j];
            ushortx4 c0 = *(const ushortx4*)(Ce + (size_t)j * 128 + q * 4);
            short8 bd0 = *(const short8*)(BD16 + (size_t)s0 * 256 + q * 8);
            ushortx4 o0;
#pragma unroll
            for (int k = 0; k < 4; ++k) {
                float en0 = bf2f(c0[k]) + bf2f((unsigned short)bd0[2 * k + 1]) + ehf[k];
                if (DO_E) {
                    es[k] += en0;
                    eq[k] += en0 * en0;
                    o0[k] = f2bf(en0);
                }
                float sg0 = 1.f / (1.f + __expf(-en0));
                den[k] += sg0;
                num[k] += sg0 * bf2f((unsigned short)bd0[2 * k]);
            }
            if (DO_E) *(ushortx4*)(Ce + (size_t)j * 128 + q * 4) = o0;
        }
        floatx4 ah = *(const floatx4*)(Ah + (size_t)d * 128 + q * 4);
        floatx4 out;
#pragma unroll
        for (int k = 0; k < 4; ++k) {
            float v = ah[k] + num[k] / (den[k] + 1e-6f);
            out[k] = v;
            hs[k] += v;
            hq[k] += v * v;
        }
        *(floatx4*)(h_new + (size_t)d * 128 + q * 4) = out;
    }
    __shared__ float ls[512];
    ls[threadIdx.x] = 0.f;
    ls[256 + threadIdx.x] = 0.f;
    __syncthreads();
#pragma unroll
    for (int k = 0; k < 4; ++k) {
        atomicAdd(&ls[q * 4 + k], hs[k]);
        atomicAdd(&ls[128 + q * 4 + k], hq[k]);
        if (DO_E) {
            atomicAdd(&ls[256 + q * 4 + k], es[k]);
            atomicAdd(&ls[384 + q * 4 + k], eq[k]);
        }
    }
    __syncthreads();
    atomicAdd(&sums[threadIdx.x], ls[threadIdx.x]);
    if (DO_E) atomicAdd(&sums[256 + threadIdx.x], ls[256 + threadIdx.x]);
}

// ---------------------------------------------------------------------------
// Finalize BN stats -> affine coefs.
// ---------------------------------------------------------------------------
__global__ void finalize_stats(const float* __restrict__ sums,
                               const float* __restrict__ gh,
                               const float* __restrict__ bh,
                               const float* __restrict__ ge,
                               const float* __restrict__ be,
                               float* __restrict__ coef, int N, int E) {
    int c = threadIdx.x;
    if (c >= 128) return;
    float muh = sums[c] / (float)N;
    float vh = fmaxf(sums[128 + c] / (float)N - muh * muh, 0.f);
    float rsh = rsqrtf(vh + 1e-5f);
    float g = gh[c], bt = bh[c];
    coef[c] = g * rsh;
    coef[128 + c] = bt - g * rsh * muh;
    float mue = sums[256 + c] / (float)E;
    float ve = fmaxf(sums[384 + c] / (float)E - mue * mue, 0.f);
    float rse = rsqrtf(ve + 1e-5f);
    float g2 = ge[c], b2 = be[c];
    coef[256 + c] = g2 * rse;
    coef[384 + c] = b2 - g2 * rse * mue;
}

// ---------------------------------------------------------------------------
// h residual update.
// ---------------------------------------------------------------------------
__global__ __launch_bounds__(256) void h_update(const float* __restrict__ h_new,
                                                const float* __restrict__ coef,
                                                float* __restrict__ h_cur,
                                                float* __restrict__ out, int N) {
    const int c = threadIdx.x & 127;
    float sa = coef[c], sb = coef[128 + c];
    int total = N * 128;
    for (int i = blockIdx.x * blockDim.x + threadIdx.x; i < total; i += gridDim.x * blockDim.x) {
        float v = h_new[i] * sa + sb;
        v = v > 0.f ? v : 0.f;
        float h = h_cur[i] + v;
        h_cur[i] = h;
        if (out) out[i] = h;
    }
}

// ---------------------------------------------------------------------------
// e residual update, vectorized: e_cur += relu(BN(e_new)), 8 bf16/thread/iter.
// ---------------------------------------------------------------------------
__global__ __launch_bounds__(256) void e_update(const unsigned short* __restrict__ e_new,
                                                const float* __restrict__ coef,
                                                unsigned short* __restrict__ e_cur, int E) {
    int total8 = E * 16;  // groups of 8 shorts
    for (int idx = blockIdx.x * blockDim.x + threadIdx.x; idx < total8;
         idx += gridDim.x * blockDim.x) {
        int c8 = (idx & 15) * 8;
        short8 en = *(const short8*)(e_new + (size_t)idx * 8);
        short8 ec = *(const short8*)(e_cur + (size_t)idx * 8);
        floatx4 sa0 = *(const floatx4*)(coef + 256 + c8);
        floatx4 sa1 = *(const floatx4*)(coef + 256 + c8 + 4);
        floatx4 sb0 = *(const floatx4*)(coef + 384 + c8);
        floatx4 sb1 = *(const floatx4*)(coef + 384 + c8 + 4);
        short8 r;
#pragma unroll
        for (int k = 0; k < 8; ++k) {
            float sa = (k < 4) ? sa0[k] : sa1[k - 4];
            float sb = (k < 4) ? sb0[k] : sb1[k - 4];
            float v = bf2f((unsigned short)en[k]) * sa + sb;
            v = v > 0.f ? v : 0.f;
            r[k] = (short)f2bf(bf2f((unsigned short)ec[k]) + v);
        }
        *(short8*)(e_cur + (size_t)idx * 8) = r;
    }
}

extern "C" void kernel_launch(void* const* d_in, const int* in_sizes, int n_in,
                              void* d_out, int out_size, void* d_ws, size_t ws_size,
                              hipStream_t stream) {
    const int N = 20000, E = 256000, L = 4;

    const float* h_in = (const float*)d_in[0];
    const float* e_in = (const float*)d_in[1];
    const int* src = (const int*)d_in[2];
    const int* dst = (const int*)d_in[3];
    const float* Wemb_h = (const float*)d_in[4];
    const float* bemb_h = (const float*)d_in[5];
    const float* Wemb_e = (const float*)d_in[6];
    const float* bemb_e = (const float*)d_in[7];
    const float* Aw = (const float*)d_in[8];
    const float* Abi = (const float*)d_in[9];
    const float* Bw = (const float*)d_in[10];
    const float* Bbi = (const float*)d_in[11];
    const float* Cw = (const float*)d_in[12];
    const float* Cbi = (const float*)d_in[13];
    const float* Dw = (const float*)d_in[14];
    const float* Dbi = (const float*)d_in[15];
    const float* Ew = (const float*)d_in[16];
    const float* Ebi = (const float*)d_in[17];
    const float* gh = (const float*)d_in[18];
    const float* bh = (const float*)d_in[19];
    const float* ge = (const float*)d_in[20];
    const float* be = (const float*)d_in[21];

    char* p = (char*)d_ws;
    auto carve = [&](size_t bytes) {
        void* r = (void*)p;
        p += ((bytes + 255) & ~(size_t)255);
        return r;
    };
    unsigned short* Wt = (unsigned short*)carve((size_t)22 * 16384 * 2);
    float* h_cur = (float*)carve((size_t)N * 128 * 4);
    unsigned short* e_cur = (unsigned short*)carve((size_t)E * 128 * 2);   // CSR order
    unsigned short* e_new = (unsigned short*)carve((size_t)E * 128 * 2);   // Ce then e_new, CSR
    float* AhB = (float*)carve((size_t)N * 128 * 4);
    unsigned short* BD16 = (unsigned short*)carve((size_t)N * 256 * 2);    // Bh/Dh interleaved
    unsigned short* Eh16 = (unsigned short*)carve((size_t)N * 128 * 2);
    float* h_newB = (float*)carve((size_t)N * 128 * 4);
    float* sums = (float*)carve(4 * 128 * 4);
    float* coef = (float*)carve(4 * 128 * 4);
    int* deg = (int*)carve((size_t)N * 4);
    int* rowptr = (int*)carve((size_t)(N + 1) * 4);
    int* cursor = (int*)carve((size_t)N * 4);
    int* eix = (int*)carve((size_t)E * 4);
    int* sx = (int*)carve((size_t)E * 4);

    // ---- CSR build ----
    hipMemsetAsync(deg, 0, (size_t)N * 4, stream);
    deg_count<<<(E + 255) / 256, 256, 0, stream>>>(dst, deg, E);
    scan_rowptr<<<1, 1024, 0, stream>>>(deg, rowptr, cursor, N);
    scatter_edges<<<(E + 255) / 256, 256, 0, stream>>>(src, dst, cursor, eix, sx, E);

    // weights -> transposed bf16 layout
    transpose_w<<<(22 * 16384 + 255) / 256, 256, 0, stream>>>(Wemb_h, Wemb_e, Aw, Bw, Cw, Dw, Ew, Wt);

    // input embeddings: h normal; e gathered into CSR order (bf16 out)
    gemm128<0, 0, 0><<<313, 256, 0, stream>>>(h_in, nullptr, Wt + 0 * 16384, bemb_h, h_cur, N / 16);
    gemm128<0, 1, 1><<<2048, 256, 0, stream>>>(e_in, eix, Wt + 1 * 16384, bemb_e, e_cur, E / 16);

    for (int l = 0; l < L; ++l) {
        int last = (l == L - 1);
        hipMemsetAsync(sums, 0, 4 * 128 * 4, stream);
        const unsigned short* WtL = Wt + (size_t)(2 + l * 5) * 16384;
        gemm_h4<<<N / 16, 256, 0, stream>>>(h_cur, WtL, Abi + l * 128, Bbi + l * 128,
                                            Dbi + l * 128, Ebi + l * 128, AhB, BD16, Eh16,
                                            N / 16);
        // Ce = e_cur @ Cw + Cb   (pure streaming GEMM, bf16 -> bf16)
        gemm128<1, 1, 0><<<2048, 256, 0, stream>>>(e_cur, nullptr, WtL + 2 * 16384, Cbi + l * 128,
                                                   e_new, E / 16);
        if (!last)
            node_aggregate<1><<<1250, 256, 0, stream>>>(e_new, BD16, Eh16, rowptr, sx, AhB,
                                                        h_newB, sums, N);
        else
            node_aggregate<0><<<1250, 256, 0, stream>>>(e_new, BD16, Eh16, rowptr, sx, AhB,
                                                        h_newB, sums, N);
        finalize_stats<<<1, 128, 0, stream>>>(sums, gh + l * 128, bh + l * 128, ge + l * 128,
                                              be + l * 128, coef, N, E);
        h_update<<<512, 256, 0, stream>>>(h_newB, coef, h_cur, last ? (float*)d_out : nullptr, N);
        if (!last) e_update<<<2048, 256, 0, stream>>>(e_new, coef, e_cur, E);
    }
}